// Round 5
// baseline (1773.008 us; speedup 1.0000x reference)
//
#include <hip/hip_runtime.h>

#define KNN 10
constexpr int N = 2048;
constexpr int M = 131072;
constexpr int D = 256;
constexpr int C = 126;

constexpr int BN = 128;          // query rows per block
constexpr int BM = 128;          // bank rows per subtile
constexpr int NSUB = 8;          // subtiles per block -> 1024 m per block
constexpr int NCHUNK = M / (BM * NSUB);     // 128 chunks
constexpr int CAND_PER_N = NCHUNK * KNN;    // 1280 candidates per query
constexpr int KSEG = D / 32;                // 8 k-segments per row-group

typedef __fp16   half2v __attribute__((ext_vector_type(2)));  // cvt_pkrtz result type
typedef _Float16 half8  __attribute__((ext_vector_type(8)));  // MFMA operand type
typedef float   float4v __attribute__((ext_vector_type(4)));

typedef const __attribute__((address_space(1))) void* gas_p;
typedef __attribute__((address_space(3))) void* las_p;

__device__ __forceinline__ void gload_lds16(const void* g, void* l) {
  __builtin_amdgcn_global_load_lds((gas_p)g, (las_p)l, 16, 0, 0);
}

// branch-free sorted-insert chain on 10 scalar (value,index) pairs,
// prefix-parameterized so one thread can hold two independent states.
#define CHAIN_P(P, v, ix)                                                    \
  do {                                                                       \
    const bool c0 = (v) < P##s0, c1 = (v) < P##s1, c2 = (v) < P##s2,         \
               c3 = (v) < P##s3, c4_ = (v) < P##s4, c5 = (v) < P##s5,        \
               c6 = (v) < P##s6, c7 = (v) < P##s7, c8 = (v) < P##s8,         \
               c9 = (v) < P##s9;                                             \
    P##s9 = c8 ? P##s8 : (c9 ? (v) : P##s9);                                 \
    P##i9 = c8 ? P##i8 : (c9 ? (ix) : P##i9);                                \
    P##s8 = c7 ? P##s7 : (c8 ? (v) : P##s8);                                 \
    P##i8 = c7 ? P##i7 : (c8 ? (ix) : P##i8);                                \
    P##s7 = c6 ? P##s6 : (c7 ? (v) : P##s7);                                 \
    P##i7 = c6 ? P##i6 : (c7 ? (ix) : P##i7);                                \
    P##s6 = c5 ? P##s5 : (c6 ? (v) : P##s6);                                 \
    P##i6 = c5 ? P##i5 : (c6 ? (ix) : P##i6);                                \
    P##s5 = c4_ ? P##s4 : (c5 ? (v) : P##s5);                                \
    P##i5 = c4_ ? P##i4 : (c5 ? (ix) : P##i5);                               \
    P##s4 = c3 ? P##s3 : (c4_ ? (v) : P##s4);                                \
    P##i4 = c3 ? P##i3 : (c4_ ? (ix) : P##i4);                               \
    P##s3 = c2 ? P##s2 : (c3 ? (v) : P##s3);                                 \
    P##i3 = c2 ? P##i2 : (c3 ? (ix) : P##i3);                                \
    P##s2 = c1 ? P##s1 : (c2 ? (v) : P##s2);                                 \
    P##i2 = c1 ? P##i1 : (c2 ? (ix) : P##i2);                                \
    P##s1 = c0 ? P##s0 : (c1 ? (v) : P##s1);                                 \
    P##i1 = c0 ? P##i0 : (c1 ? (ix) : P##i1);                                \
    P##s0 = c0 ? (v) : P##s0;                                                \
    P##i0 = c0 ? (ix) : P##i0;                                               \
  } while (0)

// ---------------- phase 0: bank row squared norms (fallback path only) -------
__global__ __launch_bounds__(256) void b2_kernel(const float* __restrict__ bank,
                                                 float* __restrict__ b2) {
  const int wave = threadIdx.x >> 6, lane = threadIdx.x & 63;
  const int m = (blockIdx.x << 2) + wave;          // 4 rows per block
  const float4 v = ((const float4*)(bank + (size_t)m * D))[lane];  // 64*4 = 256
  float s = v.x * v.x + v.y * v.y + v.z * v.z + v.w * v.w;
#pragma unroll
  for (int off = 32; off >= 1; off >>= 1) s += __shfl_down(s, off);
  if (lane == 0) b2[m] = s;
}

// ---------------- phase 0b: fp32 -> fp16 hi/lo images, MFMA-fragment layout ---
// Optionally emits row squared-norms (b2 != nullptr) -- fuses the old b2_kernel
// into the bank conversion pass, saving one full 128 MB bank read.
__global__ __launch_bounds__(256) void cvt_kernel(const float* __restrict__ src,
                                                  char* __restrict__ hi,
                                                  char* __restrict__ lo,
                                                  float* __restrict__ b2) {
  const int gid = blockIdx.x * 256 + threadIdx.x;
  const int m = gid >> 5, kg = gid & 31;           // kg: 8-element k-group
  const float4 v0 = *(const float4*)(src + (size_t)m * D + (kg << 3));
  const float4 v1 = *(const float4*)(src + (size_t)m * D + (kg << 3) + 4);
  union Pack { half2v h[4]; uint4 u; };
  Pack hh, ll;
  hh.h[0] = __builtin_amdgcn_cvt_pkrtz(v0.x, v0.y);
  hh.h[1] = __builtin_amdgcn_cvt_pkrtz(v0.z, v0.w);
  hh.h[2] = __builtin_amdgcn_cvt_pkrtz(v1.x, v1.y);
  hh.h[3] = __builtin_amdgcn_cvt_pkrtz(v1.z, v1.w);
  ll.h[0] = __builtin_amdgcn_cvt_pkrtz(v0.x - (float)hh.h[0].x, v0.y - (float)hh.h[0].y);
  ll.h[1] = __builtin_amdgcn_cvt_pkrtz(v0.z - (float)hh.h[1].x, v0.w - (float)hh.h[1].y);
  ll.h[2] = __builtin_amdgcn_cvt_pkrtz(v1.x - (float)hh.h[2].x, v1.y - (float)hh.h[2].y);
  ll.h[3] = __builtin_amdgcn_cvt_pkrtz(v1.z - (float)hh.h[3].x, v1.w - (float)hh.h[3].y);
  const size_t off = (((size_t)(m >> 4) * KSEG + (kg >> 2)) << 10) +
                     (((m & 15) | ((kg & 3) << 4)) << 4);
  *(uint4*)(hi + off) = hh.u;
  *(uint4*)(lo + off) = ll.u;
  if (b2 != nullptr) {
    float s = v0.x * v0.x + v0.y * v0.y + v0.z * v0.z + v0.w * v0.w +
              v1.x * v1.x + v1.y * v1.y + v1.z * v1.z + v1.w * v1.w;
#pragma unroll
    for (int o = 16; o >= 1; o >>= 1) s += __shfl_xor(s, o);  // across 32 kg lanes
    if (kg == 0) b2[m] = s;
  }
}

// ---------------- phase 1 (fast): pipelined DMA MFMA GEMM + per-chunk top-10 ---
// LDS = 32 KB TOTAL: the fp32 64x128 score tile OVERLAYS the A/B staging region
// (Ah 8K | Al 8K | Bh 8K | Bl 8K). They never coexist: the next-sub k0 prefetch
// was moved from the score phase to the sub top, behind a scan-complete barrier,
// so staging is dead during score write/scan and score is dead during the k-loop.
// 32 KB + VGPR 128 -> 3 blocks/CU (launch_bounds cap 170, ample margin over 128;
// round-3 lesson: never cap below actual pressure -- acc spill costs 3x).
// Two-barrier k-step cadence preserved (round-2 lesson: it is the L2 metronome;
// 6 co-resident sharers per chunk now instead of 4).
__global__ __launch_bounds__(256, 3) void knn_chunk_mfma(
    const char* __restrict__ pAhi, const char* __restrict__ pAlo,
    const char* __restrict__ pBhi, const char* __restrict__ pBlo,
    const float* __restrict__ b2g, float* __restrict__ cand_s,
    int* __restrict__ cand_i) {
  __shared__ char smem[32768];
  float* score = (float*)smem;               // overlays staging
  char* stg = smem;                          // same region

  const int tid = threadIdx.x;
  const int lane = tid & 63;
  const int wave = tid >> 6;
  const int wx = wave & 1, wy = wave >> 1;   // 2x2 wave grid, 64x64 per wave
  const int n0 = blockIdx.y * BN;
  const int chunk = blockIdx.x;
  const int ag0 = n0 >> 4;                   // A row-group base

  // two top-10 states: A = pass-0 query (tid&63), B = pass-1 query 64+(tid&63)
  float As0 = 3e38f, As1 = 3e38f, As2 = 3e38f, As3 = 3e38f, As4 = 3e38f,
        As5 = 3e38f, As6 = 3e38f, As7 = 3e38f, As8 = 3e38f, As9 = 3e38f;
  int Ai0 = -1, Ai1 = -1, Ai2 = -1, Ai3 = -1, Ai4 = -1,
      Ai5 = -1, Ai6 = -1, Ai7 = -1, Ai8 = -1, Ai9 = -1;
  float Bs0 = 3e38f, Bs1 = 3e38f, Bs2 = 3e38f, Bs3 = 3e38f, Bs4 = 3e38f,
        Bs5 = 3e38f, Bs6 = 3e38f, Bs7 = 3e38f, Bs8 = 3e38f, Bs9 = 3e38f;
  int Bi0 = -1, Bi1 = -1, Bi2 = -1, Bi3 = -1, Bi4 = -1,
      Bi5 = -1, Bi6 = -1, Bi7 = -1, Bi8 = -1, Bi9 = -1;

  auto stage = [&](int bg0, int kseg) {
#pragma unroll
    for (int t = 0; t < 2; ++t) {
      const int grp = (wave << 1) + t;       // 0..7
      const size_t aoff = (((size_t)(ag0 + grp) * KSEG + kseg) << 10) + (lane << 4);
      const size_t boff = (((size_t)(bg0 + grp) * KSEG + kseg) << 10) + (lane << 4);
      const int ldst = (grp << 10) + (lane << 4);
      gload_lds16(pAhi + aoff, stg + ldst);
      gload_lds16(pAlo + aoff, stg + 8192 + ldst);
      gload_lds16(pBhi + boff, stg + 16384 + ldst);
      gload_lds16(pBlo + boff, stg + 24576 + ldst);
    }
  };

  for (int sub = 0; sub < NSUB; ++sub) {
    const int m0 = (chunk * NSUB + sub) * BM;
    const int bg0 = m0 >> 4;
    float4v acc[4][4];
#pragma unroll
    for (int i = 0; i < 4; ++i)
#pragma unroll
      for (int j = 0; j < 4; ++j) acc[i][j] = (float4v)(0.0f);

    // (z) previous sub's scan readers are done -> staging region is free.
    __syncthreads();
    stage(bg0, 0);

    for (int k = 0; k < KSEG; ++k) {
      __syncthreads();                       // (a) staged seg k visible (drains DMA)
      half8 ah[4], al[4], bh[4], bl[4];
#pragma unroll
      for (int t = 0; t < 4; ++t) {
        const int ao = (((wy << 2) + t) << 10) + (lane << 4);
        ah[t] = *(half8*)(stg + ao);
        al[t] = *(half8*)(stg + 8192 + ao);
        const int bo = (((wx << 2) + t) << 10) + (lane << 4);
        bh[t] = *(half8*)(stg + 16384 + bo);
        bl[t] = *(half8*)(stg + 24576 + bo);
      }
      __syncthreads();                       // (b) fragments consumed, staging free
      if (k < KSEG - 1) stage(bg0, k + 1);   // DMA flies under the MFMAs
#pragma unroll
      for (int i = 0; i < 4; ++i)
#pragma unroll
        for (int j = 0; j < 4; ++j) {
          acc[i][j] = __builtin_amdgcn_mfma_f32_16x16x32_f16(ah[i], bh[j], acc[i][j], 0, 0, 0);
          acc[i][j] = __builtin_amdgcn_mfma_f32_16x16x32_f16(ah[i], bl[j], acc[i][j], 0, 0, 0);
          acc[i][j] = __builtin_amdgcn_mfma_f32_16x16x32_f16(al[i], bh[j], acc[i][j], 0, 0, 0);
        }
    }

    float b2v[4];
#pragma unroll
    for (int j = 0; j < 4; ++j)
      b2v[j] = b2g[m0 + (wx << 6) + (j << 4) + (lane & 15)];

    // two passes: score rows 0..63 (waves wy==0) then 64..127 (wy==1);
    // ALL 256 threads scan each pass: thread t -> row t&63, quarter t>>6.
#pragma unroll
    for (int pp = 0; pp < 2; ++pp) {
      __syncthreads();                       // last frag reads / prev scan done
      if (wy == pp) {
        // C/D layout: col=lane&15, row=(lane>>4)*4+reg  [m89]
#pragma unroll
        for (int i = 0; i < 4; ++i)
#pragma unroll
          for (int j = 0; j < 4; ++j) {
            const int colw = (wx << 6) + (j << 4) + (lane & 15);
#pragma unroll
            for (int r = 0; r < 4; ++r) {
              const int row = (i << 4) + ((lane >> 4) << 2) + r;
              score[(row << 7) + ((((colw >> 2) ^ (row & 31)) << 2) | (colw & 3))] =
                  fmaf(-2.0f, acc[i][j][r], b2v[j]);
            }
          }
      }
      __syncthreads();
      {
        const int lr = tid & 63;             // query row within this pass
        const int qd = tid >> 6;             // quarter 0..3 (== wave id)
        const float* srow = score + (lr << 7);
        const int key = lr & 31;
        const int cb4 = qd << 3;
#pragma unroll 4
        for (int g = 0; g < 8; ++g) {
          const float4 v = *(const float4*)(srow + (((cb4 + g) ^ key) << 2));
          const int ib = m0 + (qd << 5) + (g << 2);
          if (pp == 0) {
            if (v.x < As9) CHAIN_P(A, v.x, ib);
            if (v.y < As9) CHAIN_P(A, v.y, ib + 1);
            if (v.z < As9) CHAIN_P(A, v.z, ib + 2);
            if (v.w < As9) CHAIN_P(A, v.w, ib + 3);
          } else {
            if (v.x < Bs9) CHAIN_P(B, v.x, ib);
            if (v.y < Bs9) CHAIN_P(B, v.y, ib + 1);
            if (v.z < Bs9) CHAIN_P(B, v.z, ib + 2);
            if (v.w < Bs9) CHAIN_P(B, v.w, ib + 3);
          }
        }
      }
    }
  }

  // merge the 4 quarter-scanners per query, two rounds (pass-A, pass-B queries)
  __syncthreads();
  float* mg = (float*)smem;                  // 256*20*4 = 20 KB, fits
  {
    float* p_ = mg + tid * 20;
    p_[0] = As0; p_[1] = As1; p_[2] = As2; p_[3] = As3; p_[4] = As4;
    p_[5] = As5; p_[6] = As6; p_[7] = As7; p_[8] = As8; p_[9] = As9;
    int* q_ = (int*)(p_ + 10);
    q_[0] = Ai0; q_[1] = Ai1; q_[2] = Ai2; q_[3] = Ai3; q_[4] = Ai4;
    q_[5] = Ai5; q_[6] = Ai6; q_[7] = Ai7; q_[8] = Ai8; q_[9] = Ai9;
  }
  __syncthreads();
  if (tid < 64) {                            // owns quarter 0 of query tid
#pragma unroll
    for (int qd = 1; qd < 4; ++qd) {
      const float* p_ = mg + ((qd << 6) + tid) * 20;
      const int* q_ = (const int*)(p_ + 10);
#pragma unroll
      for (int q = 0; q < KNN; ++q) {
        const float v = p_[q];
        const int ix = q_[q];
        if (v < As9) CHAIN_P(A, v, ix);
      }
    }
    const size_t base = ((size_t)(n0 + tid) * NCHUNK + chunk) * KNN;
    cand_s[base + 0] = As0; cand_s[base + 1] = As1; cand_s[base + 2] = As2;
    cand_s[base + 3] = As3; cand_s[base + 4] = As4; cand_s[base + 5] = As5;
    cand_s[base + 6] = As6; cand_s[base + 7] = As7; cand_s[base + 8] = As8;
    cand_s[base + 9] = As9;
    cand_i[base + 0] = Ai0; cand_i[base + 1] = Ai1; cand_i[base + 2] = Ai2;
    cand_i[base + 3] = Ai3; cand_i[base + 4] = Ai4; cand_i[base + 5] = Ai5;
    cand_i[base + 6] = Ai6; cand_i[base + 7] = Ai7; cand_i[base + 8] = Ai8;
    cand_i[base + 9] = Ai9;
  }
  __syncthreads();
  {
    float* p_ = mg + tid * 20;
    p_[0] = Bs0; p_[1] = Bs1; p_[2] = Bs2; p_[3] = Bs3; p_[4] = Bs4;
    p_[5] = Bs5; p_[6] = Bs6; p_[7] = Bs7; p_[8] = Bs8; p_[9] = Bs9;
    int* q_ = (int*)(p_ + 10);
    q_[0] = Bi0; q_[1] = Bi1; q_[2] = Bi2; q_[3] = Bi3; q_[4] = Bi4;
    q_[5] = Bi5; q_[6] = Bi6; q_[7] = Bi7; q_[8] = Bi8; q_[9] = Bi9;
  }
  __syncthreads();
  if (tid < 64) {
#pragma unroll
    for (int qd = 1; qd < 4; ++qd) {
      const float* p_ = mg + ((qd << 6) + tid) * 20;
      const int* q_ = (const int*)(p_ + 10);
#pragma unroll
      for (int q = 0; q < KNN; ++q) {
        const float v = p_[q];
        const int ix = q_[q];
        if (v < Bs9) CHAIN_P(B, v, ix);
      }
    }
    const size_t base = ((size_t)(n0 + 64 + tid) * NCHUNK + chunk) * KNN;
    cand_s[base + 0] = Bs0; cand_s[base + 1] = Bs1; cand_s[base + 2] = Bs2;
    cand_s[base + 3] = Bs3; cand_s[base + 4] = Bs4; cand_s[base + 5] = Bs5;
    cand_s[base + 6] = Bs6; cand_s[base + 7] = Bs7; cand_s[base + 8] = Bs8;
    cand_s[base + 9] = Bs9;
    cand_i[base + 0] = Bi0; cand_i[base + 1] = Bi1; cand_i[base + 2] = Bi2;
    cand_i[base + 3] = Bi3; cand_i[base + 4] = Bi4; cand_i[base + 5] = Bi5;
    cand_i[base + 6] = Bi6; cand_i[base + 7] = Bi7; cand_i[base + 8] = Bi8;
    cand_i[base + 9] = Bi9;
  }
}

// ---------------- phase 1 (fallback, round-3 proven): in-kernel conversion ----
__global__ __launch_bounds__(256, 2) void knn_chunk_fallback(
    const float* __restrict__ Ag, const float* __restrict__ Bg,
    const float* __restrict__ b2g, float* __restrict__ cand_s,
    int* __restrict__ cand_i) {
  __shared__ float smemf[64 * 130];
  char* lds = (char*)smemf;
  float (*S64)[130] = (float(*)[130])smemf;

  const int tid = threadIdx.x;
  const int lane = tid & 63;
  const int wave = tid >> 6;
  const int wx = wave & 1, wy = wave >> 1;
  const int n0 = blockIdx.y * BN;
  const int chunk = blockIdx.x;

  float ts[KNN];
  int ti_[KNN];
#pragma unroll
  for (int q = 0; q < KNN; ++q) { ts[q] = 3.0e38f; ti_[q] = -1; }

  for (int sub = 0; sub < NSUB; ++sub) {
    const int m0 = (chunk * NSUB + sub) * BM;
    float4v acc[4][4];
#pragma unroll
    for (int i = 0; i < 4; ++i)
#pragma unroll
      for (int j = 0; j < 4; ++j) acc[i][j] = (float4v)(0.0f);

    for (int k0 = 0; k0 < D; k0 += 32) {
      __syncthreads();
#pragma unroll
      for (int r = 0; r < 4; ++r) {
        const int id = tid + (r << 8);
        const int n = id >> 3;
        const int c4 = id & 7;
        const int k = c4 << 2;
        const int off = ((n >> 4) << 10) + (((n & 15) | ((k >> 3) << 4)) << 4) +
                        ((c4 & 1) << 3);
        {
          const float4 v = *(const float4*)(Ag + (size_t)(n0 + n) * D + k0 + k);
          const half2v h01 = __builtin_amdgcn_cvt_pkrtz(v.x, v.y);
          const half2v h23 = __builtin_amdgcn_cvt_pkrtz(v.z, v.w);
          const half2v l01 =
              __builtin_amdgcn_cvt_pkrtz(v.x - (float)h01.x, v.y - (float)h01.y);
          const half2v l23 =
              __builtin_amdgcn_cvt_pkrtz(v.z - (float)h23.x, v.w - (float)h23.y);
          union { half2v h[2]; uint2 u; } hh, ll;
          hh.h[0] = h01; hh.h[1] = h23;
          ll.h[0] = l01; ll.h[1] = l23;
          *(uint2*)(lds + off) = hh.u;
          *(uint2*)(lds + 8192 + off) = ll.u;
        }
        {
          const float4 v = *(const float4*)(Bg + (size_t)(m0 + n) * D + k0 + k);
          const half2v h01 = __builtin_amdgcn_cvt_pkrtz(v.x, v.y);
          const half2v h23 = __builtin_amdgcn_cvt_pkrtz(v.z, v.w);
          const half2v l01 =
              __builtin_amdgcn_cvt_pkrtz(v.x - (float)h01.x, v.y - (float)h01.y);
          const half2v l23 =
              __builtin_amdgcn_cvt_pkrtz(v.z - (float)h23.x, v.w - (float)h23.y);
          union { half2v h[2]; uint2 u; } hh, ll;
          hh.h[0] = h01; hh.h[1] = h23;
          ll.h[0] = l01; ll.h[1] = l23;
          *(uint2*)(lds + 16384 + off) = hh.u;
          *(uint2*)(lds + 24576 + off) = ll.u;
        }
      }
      __syncthreads();
      half8 ah[4], al[4], bh[4], bl[4];
#pragma unroll
      for (int q = 0; q < 4; ++q) {
        const int ao = ((((wy << 2) + q) << 10)) + (lane << 4);
        ah[q] = *(half8*)(lds + ao);
        al[q] = *(half8*)(lds + 8192 + ao);
        const int bo = ((((wx << 2) + q) << 10)) + (lane << 4);
        bh[q] = *(half8*)(lds + 16384 + bo);
        bl[q] = *(half8*)(lds + 24576 + bo);
      }
#pragma unroll
      for (int i = 0; i < 4; ++i)
#pragma unroll
        for (int j = 0; j < 4; ++j) {
          acc[i][j] = __builtin_amdgcn_mfma_f32_16x16x32_f16(ah[i], bh[j], acc[i][j], 0, 0, 0);
          acc[i][j] = __builtin_amdgcn_mfma_f32_16x16x32_f16(ah[i], bl[j], acc[i][j], 0, 0, 0);
          acc[i][j] = __builtin_amdgcn_mfma_f32_16x16x32_f16(al[i], bh[j], acc[i][j], 0, 0, 0);
        }
    }

    float b2v[4];
#pragma unroll
    for (int j = 0; j < 4; ++j)
      b2v[j] = b2g[m0 + (wx << 6) + (j << 4) + (lane & 15)];

    for (int p = 0; p < 2; ++p) {
      __syncthreads();
      if (wy == p) {
#pragma unroll
        for (int i = 0; i < 4; ++i)
#pragma unroll
          for (int j = 0; j < 4; ++j)
#pragma unroll
            for (int r = 0; r < 4; ++r)
              S64[(i << 4) + ((lane >> 4) << 2) + r]
                 [(wx << 6) + (j << 4) + (lane & 15)] =
                  fmaf(-2.0f, acc[i][j][r], b2v[j]);
      }
      __syncthreads();
      const int rr = tid & 127;
      if ((rr >> 6) == p) {
        const int lr = rr & 63;
        const int cbase = (tid >> 7) << 6;
        float cut = ts[KNN - 1];
        for (int c = 0; c < 64; ++c) {
          const float s = S64[lr][cbase + c];
          if (s < cut) {
            float cs = s;
            int ci = m0 + cbase + c;
#pragma unroll
            for (int q = 0; q < KNN; ++q) {
              if (cs < ts[q]) {
                const float tf = ts[q]; ts[q] = cs; cs = tf;
                const int tv = ti_[q]; ti_[q] = ci; ci = tv;
              }
            }
            cut = ts[KNN - 1];
          }
        }
      }
    }
  }

  __syncthreads();
  const int r = tid & 127, h = tid >> 7;
  float* mg = (float*)smemf;
  if (h == 1) {
#pragma unroll
    for (int q = 0; q < KNN; ++q) {
      mg[r * 20 + q] = ts[q];
      ((int*)mg)[r * 20 + 10 + q] = ti_[q];
    }
  }
  __syncthreads();
  if (h == 0) {
#pragma unroll
    for (int q = 0; q < KNN; ++q) {
      const float s = mg[r * 20 + q];
      const int idx = ((int*)mg)[r * 20 + 10 + q];
      if (s < ts[KNN - 1]) {
        float cs = s;
        int ci = idx;
#pragma unroll
        for (int u = 0; u < KNN; ++u) {
          if (cs < ts[u]) {
            const float tf = ts[u]; ts[u] = cs; cs = tf;
            const int tv = ti_[u]; ti_[u] = ci; ci = tv;
          }
        }
      }
    }
    const size_t base = ((size_t)(n0 + r) * NCHUNK + chunk) * KNN;
#pragma unroll
    for (int q = 0; q < KNN; ++q) {
      cand_s[base + q] = ts[q];
      cand_i[base + q] = ti_[q];
    }
  }
}

// ---------------- phase 2: global top-10 merge + probs mean + argmax ----------------
__global__ __launch_bounds__(256) void knn_finalize_kernel(
    const float* __restrict__ cand_s, const int* __restrict__ cand_i,
    const float* __restrict__ probs, float* __restrict__ out) {
  const int n = blockIdx.x, t = threadIdx.x;
  const size_t cb = (size_t)n * CAND_PER_N;

  float sc[5];
  int id_[5];
#pragma unroll
  for (int r = 0; r < 5; ++r) {
    sc[r] = cand_s[cb + t + (r << 8)];
    id_[r] = cand_i[cb + t + (r << 8)];
  }

  __shared__ float rs[4];
  __shared__ int rm[4];
  __shared__ int win[KNN];

  for (int round = 0; round < KNN; ++round) {
    float bs = 3.0e38f;
    int bm = 0x7fffffff;
#pragma unroll
    for (int r = 0; r < 5; ++r) {
      const bool better =
          (id_[r] >= 0) && (sc[r] < bs || (sc[r] == bs && id_[r] < bm));
      if (better) { bs = sc[r]; bm = id_[r]; }
    }
#pragma unroll
    for (int off = 32; off >= 1; off >>= 1) {
      const float os = __shfl_down(bs, off);
      const int om = __shfl_down(bm, off);
      if (os < bs || (os == bs && om < bm)) { bs = os; bm = om; }
    }
    if ((t & 63) == 0) { rs[t >> 6] = bs; rm[t >> 6] = bm; }
    __syncthreads();
    if (t == 0) {
      float fb = rs[0]; int fm = rm[0];
      for (int w = 1; w < 4; ++w)
        if (rs[w] < fb || (rs[w] == fb && rm[w] < fm)) { fb = rs[w]; fm = rm[w]; }
      win[round] = fm;
    }
    __syncthreads();
    const int wmv = win[round];
#pragma unroll
    for (int r = 0; r < 5; ++r)
      if (id_[r] == wmv) id_[r] = -1;  // m indices are globally unique
  }

  __shared__ float pv[128];
  float myp = -1.0e30f;
  if (t < C) {
    float acc = 0.0f;
#pragma unroll
    for (int q = 0; q < KNN; ++q) acc += probs[(size_t)win[q] * C + t];
    myp = acc * (1.0f / KNN);
    out[N + (size_t)n * C + t] = myp;
  }
  if (t < 128) pv[t] = myp;
  __syncthreads();
  if (t == 0) {
    float bv = pv[0];
    int bi = 0;
    for (int c = 1; c < C; ++c)
      if (pv[c] > bv) { bv = pv[c]; bi = c; }
    out[n] = (float)bi;
  }
}

extern "C" void kernel_launch(void* const* d_in, const int* in_sizes, int n_in,
                              void* d_out, int out_size, void* d_ws, size_t ws_size,
                              hipStream_t stream) {
  const float* features = (const float*)d_in[0];  // (N, D)
  const float* bank = (const float*)d_in[1];      // (M, D)
  const float* probs = (const float*)d_in[2];     // (M, C)
  float* out = (float*)d_out;                     // [labels(N) | probs(N*C)]

  // ws layout (fast path):
  // b2 (0.5 MB) | cand_s (10.5 MB) | cand_i (10.5 MB) | Ahi,Alo (1 MB ea) | Bhi,Blo (64 MB ea)
  float* b2 = (float*)d_ws;
  float* cand_s = b2 + M;
  int* cand_i = (int*)(cand_s + (size_t)N * CAND_PER_N);
  char* Ahi = (char*)(cand_i + (size_t)N * CAND_PER_N);
  char* Alo = Ahi + (size_t)N * D * 2;
  char* Bhi = Alo + (size_t)N * D * 2;
  char* Blo = Bhi + (size_t)M * D * 2;
  const size_t NEED_FAST =
      (size_t)M * 4 + (size_t)N * CAND_PER_N * 8 + (size_t)N * D * 4 + (size_t)M * D * 4;

  if (ws_size >= NEED_FAST) {
    cvt_kernel<<<(N * 32) / 256, 256, 0, stream>>>(features, Ahi, Alo, nullptr);
    cvt_kernel<<<(M * 32) / 256, 256, 0, stream>>>(bank, Bhi, Blo, b2);  // fused b2
    knn_chunk_mfma<<<dim3(NCHUNK, N / BN), 256, 0, stream>>>(Ahi, Alo, Bhi, Blo,
                                                             b2, cand_s, cand_i);
  } else {
    b2_kernel<<<M / 4, 256, 0, stream>>>(bank, b2);
    knn_chunk_fallback<<<dim3(NCHUNK, N / BN), 256, 0, stream>>>(features, bank,
                                                                 b2, cand_s, cand_i);
  }
  knn_finalize_kernel<<<N, 256, 0, stream>>>(cand_s, cand_i, probs, out);
}

// Round 8
// 963.983 us; speedup vs baseline: 1.8393x; 1.8393x over previous
//
#include <hip/hip_runtime.h>

#define KNN 10
constexpr int N = 2048;
constexpr int M = 131072;
constexpr int D = 256;
constexpr int C = 126;

constexpr int BN = 128;          // query rows per block
constexpr int BM = 128;          // bank rows per subtile
constexpr int NSUB = 8;          // subtiles per block -> 1024 m per block
constexpr int NCHUNK = M / (BM * NSUB);     // 128 chunks
constexpr int CAND_PER_N = NCHUNK * KNN;    // 1280 candidates per query
constexpr int KSEG = D / 32;                // 8 k-segments per row-group
constexpr int STG = 32768;                  // staging region offset in LDS

typedef __fp16   half2v __attribute__((ext_vector_type(2)));  // cvt_pkrtz result type
typedef _Float16 half8  __attribute__((ext_vector_type(8)));  // MFMA operand type
typedef float   float4v __attribute__((ext_vector_type(4)));

typedef const __attribute__((address_space(1))) void* gas_p;
typedef __attribute__((address_space(3))) void* las_p;

__device__ __forceinline__ void gload_lds16(const void* g, void* l) {
  __builtin_amdgcn_global_load_lds((gas_p)g, (las_p)l, 16, 0, 0);
}

// branch-free sorted-insert chain on 10 scalar (value,index) pairs,
// prefix-parameterized so one thread can hold two independent states.
#define CHAIN_P(P, v, ix)                                                    \
  do {                                                                       \
    const bool c0 = (v) < P##s0, c1 = (v) < P##s1, c2 = (v) < P##s2,         \
               c3 = (v) < P##s3, c4_ = (v) < P##s4, c5 = (v) < P##s5,        \
               c6 = (v) < P##s6, c7 = (v) < P##s7, c8 = (v) < P##s8,         \
               c9 = (v) < P##s9;                                             \
    P##s9 = c8 ? P##s8 : (c9 ? (v) : P##s9);                                 \
    P##i9 = c8 ? P##i8 : (c9 ? (ix) : P##i9);                                \
    P##s8 = c7 ? P##s7 : (c8 ? (v) : P##s8);                                 \
    P##i8 = c7 ? P##i7 : (c8 ? (ix) : P##i8);                                \
    P##s7 = c6 ? P##s6 : (c7 ? (v) : P##s7);                                 \
    P##i7 = c6 ? P##i6 : (c7 ? (ix) : P##i7);                                \
    P##s6 = c5 ? P##s5 : (c6 ? (v) : P##s6);                                 \
    P##i6 = c5 ? P##i5 : (c6 ? (ix) : P##i6);                                \
    P##s5 = c4_ ? P##s4 : (c5 ? (v) : P##s5);                                \
    P##i5 = c4_ ? P##i4 : (c5 ? (ix) : P##i5);                               \
    P##s4 = c3 ? P##s3 : (c4_ ? (v) : P##s4);                                \
    P##i4 = c3 ? P##i3 : (c4_ ? (ix) : P##i4);                               \
    P##s3 = c2 ? P##s2 : (c3 ? (v) : P##s3);                                 \
    P##i3 = c2 ? P##i2 : (c3 ? (ix) : P##i3);                                \
    P##s2 = c1 ? P##s1 : (c2 ? (v) : P##s2);                                 \
    P##i2 = c1 ? P##i1 : (c2 ? (ix) : P##i2);                                \
    P##s1 = c0 ? P##s0 : (c1 ? (v) : P##s1);                                 \
    P##i1 = c0 ? P##i0 : (c1 ? (ix) : P##i1);                                \
    P##s0 = c0 ? (v) : P##s0;                                                \
    P##i0 = c0 ? (ix) : P##i0;                                               \
  } while (0)

// ---------------- phase 0: bank row squared norms (fallback path only) -------
__global__ __launch_bounds__(256) void b2_kernel(const float* __restrict__ bank,
                                                 float* __restrict__ b2) {
  const int wave = threadIdx.x >> 6, lane = threadIdx.x & 63;
  const int m = (blockIdx.x << 2) + wave;          // 4 rows per block
  const float4 v = ((const float4*)(bank + (size_t)m * D))[lane];  // 64*4 = 256
  float s = v.x * v.x + v.y * v.y + v.z * v.z + v.w * v.w;
#pragma unroll
  for (int off = 32; off >= 1; off >>= 1) s += __shfl_down(s, off);
  if (lane == 0) b2[m] = s;
}

// ---------------- phase 0b: fp32 -> fp16 hi/lo images, MFMA-fragment layout ---
// Optionally emits row squared-norms (b2 != nullptr) -- fuses the old b2_kernel
// into the bank conversion pass, saving one full 128 MB bank read.
__global__ __launch_bounds__(256) void cvt_kernel(const float* __restrict__ src,
                                                  char* __restrict__ hi,
                                                  char* __restrict__ lo,
                                                  float* __restrict__ b2) {
  const int gid = blockIdx.x * 256 + threadIdx.x;
  const int m = gid >> 5, kg = gid & 31;           // kg: 8-element k-group
  const float4 v0 = *(const float4*)(src + (size_t)m * D + (kg << 3));
  const float4 v1 = *(const float4*)(src + (size_t)m * D + (kg << 3) + 4);
  union Pack { half2v h[4]; uint4 u; };
  Pack hh, ll;
  hh.h[0] = __builtin_amdgcn_cvt_pkrtz(v0.x, v0.y);
  hh.h[1] = __builtin_amdgcn_cvt_pkrtz(v0.z, v0.w);
  hh.h[2] = __builtin_amdgcn_cvt_pkrtz(v1.x, v1.y);
  hh.h[3] = __builtin_amdgcn_cvt_pkrtz(v1.z, v1.w);
  ll.h[0] = __builtin_amdgcn_cvt_pkrtz(v0.x - (float)hh.h[0].x, v0.y - (float)hh.h[0].y);
  ll.h[1] = __builtin_amdgcn_cvt_pkrtz(v0.z - (float)hh.h[1].x, v0.w - (float)hh.h[1].y);
  ll.h[2] = __builtin_amdgcn_cvt_pkrtz(v1.x - (float)hh.h[2].x, v1.y - (float)hh.h[2].y);
  ll.h[3] = __builtin_amdgcn_cvt_pkrtz(v1.z - (float)hh.h[3].x, v1.w - (float)hh.h[3].y);
  const size_t off = (((size_t)(m >> 4) * KSEG + (kg >> 2)) << 10) +
                     (((m & 15) | ((kg & 3) << 4)) << 4);
  *(uint4*)(hi + off) = hh.u;
  *(uint4*)(lo + off) = ll.u;
  if (b2 != nullptr) {
    float s = v0.x * v0.x + v0.y * v0.y + v0.z * v0.z + v0.w * v0.w +
              v1.x * v1.x + v1.y * v1.y + v1.z * v1.z + v1.w * v1.w;
#pragma unroll
    for (int o = 16; o >= 1; o >>= 1) s += __shfl_xor(s, o);  // across 32 kg lanes
    if (kg == 0) b2[m] = s;
  }
}

// ---------------- phase 1 (fast): pipelined DMA MFMA GEMM + per-chunk top-10 ---
// Round-4 proven skeleton (766us knn / 977us total, verified): 64K LDS, (256,2),
// A+B staged via global_load_lds, two-barrier k-step cadence (the L2-sharing
// metronome), all-256-thread quarter-scan, dual top-10 state per thread.
// Closed levers (session ledger):
//  - (256,3) occupancy: true pressure = 128 VGPR + 64 AGPR = 192/wave; any
//    3-wave cap spills acc to scratch (84 VGPR + 300-680 MB WRITE signature).
//  - single-barrier dbuf: breaks the L2 metronome (FETCH doubles, +190us).
//  - tau/atomicMin threshold seeding: two correctness failures (rounds 6/7,
//    identical absmax) -- construct dropped.
__global__ __launch_bounds__(256, 2) void knn_chunk_mfma(
    const char* __restrict__ pAhi, const char* __restrict__ pAlo,
    const char* __restrict__ pBhi, const char* __restrict__ pBlo,
    const float* __restrict__ b2g, float* __restrict__ cand_s,
    int* __restrict__ cand_i) {
  __shared__ char smem[65536];
  float* score = (float*)smem;
  char* stg = smem + STG;

  const int tid = threadIdx.x;
  const int lane = tid & 63;
  const int wave = tid >> 6;
  const int wx = wave & 1, wy = wave >> 1;   // 2x2 wave grid, 64x64 per wave
  const int n0 = blockIdx.y * BN;
  const int chunk = blockIdx.x;
  const int ag0 = n0 >> 4;                   // A row-group base

  // two top-10 states: A = pass-0 query (tid&63), B = pass-1 query 64+(tid&63)
  float As0 = 3e38f, As1 = 3e38f, As2 = 3e38f, As3 = 3e38f, As4 = 3e38f,
        As5 = 3e38f, As6 = 3e38f, As7 = 3e38f, As8 = 3e38f, As9 = 3e38f;
  int Ai0 = -1, Ai1 = -1, Ai2 = -1, Ai3 = -1, Ai4 = -1,
      Ai5 = -1, Ai6 = -1, Ai7 = -1, Ai8 = -1, Ai9 = -1;
  float Bs0 = 3e38f, Bs1 = 3e38f, Bs2 = 3e38f, Bs3 = 3e38f, Bs4 = 3e38f,
        Bs5 = 3e38f, Bs6 = 3e38f, Bs7 = 3e38f, Bs8 = 3e38f, Bs9 = 3e38f;
  int Bi0 = -1, Bi1 = -1, Bi2 = -1, Bi3 = -1, Bi4 = -1,
      Bi5 = -1, Bi6 = -1, Bi7 = -1, Bi8 = -1, Bi9 = -1;

  auto stage = [&](int bg0, int kseg) {
#pragma unroll
    for (int t = 0; t < 2; ++t) {
      const int grp = (wave << 1) + t;       // 0..7
      const size_t aoff = (((size_t)(ag0 + grp) * KSEG + kseg) << 10) + (lane << 4);
      const size_t boff = (((size_t)(bg0 + grp) * KSEG + kseg) << 10) + (lane << 4);
      const int ldst = (grp << 10) + (lane << 4);
      gload_lds16(pAhi + aoff, stg + ldst);
      gload_lds16(pAlo + aoff, stg + 8192 + ldst);
      gload_lds16(pBhi + boff, stg + 16384 + ldst);
      gload_lds16(pBlo + boff, stg + 24576 + ldst);
    }
  };

  // bootstrap: stage sub 0 / k-seg 0
  stage((chunk * NSUB) * BM >> 4, 0);

  for (int sub = 0; sub < NSUB; ++sub) {
    const int m0 = (chunk * NSUB + sub) * BM;
    const int bg0 = m0 >> 4;
    float4v acc[4][4];
#pragma unroll
    for (int i = 0; i < 4; ++i)
#pragma unroll
      for (int j = 0; j < 4; ++j) acc[i][j] = (float4v)(0.0f);

    for (int k = 0; k < KSEG; ++k) {
      __syncthreads();                       // staged seg k visible (drains DMA)
      half8 ah[4], al[4], bh[4], bl[4];
#pragma unroll
      for (int t = 0; t < 4; ++t) {
        const int ao = (((wy << 2) + t) << 10) + (lane << 4);
        ah[t] = *(half8*)(stg + ao);
        al[t] = *(half8*)(stg + 8192 + ao);
        const int bo = (((wx << 2) + t) << 10) + (lane << 4);
        bh[t] = *(half8*)(stg + 16384 + bo);
        bl[t] = *(half8*)(stg + 24576 + bo);
      }
      __syncthreads();                       // fragments consumed, staging free
      if (k < KSEG - 1) stage(bg0, k + 1);   // DMA flies under the MFMAs
      else if (sub < NSUB - 1) stage(bg0 + 8, 0);  // hidden under score phase
#pragma unroll
      for (int i = 0; i < 4; ++i)
#pragma unroll
        for (int j = 0; j < 4; ++j) {
          acc[i][j] = __builtin_amdgcn_mfma_f32_16x16x32_f16(ah[i], bh[j], acc[i][j], 0, 0, 0);
          acc[i][j] = __builtin_amdgcn_mfma_f32_16x16x32_f16(ah[i], bl[j], acc[i][j], 0, 0, 0);
          acc[i][j] = __builtin_amdgcn_mfma_f32_16x16x32_f16(al[i], bh[j], acc[i][j], 0, 0, 0);
        }
    }

    float b2v[4];
#pragma unroll
    for (int j = 0; j < 4; ++j)
      b2v[j] = b2g[m0 + (wx << 6) + (j << 4) + (lane & 15)];

    // two passes: score rows 0..63 (waves wy==0) then 64..127 (wy==1);
    // ALL 256 threads scan each pass: thread t -> row t&63, quarter t>>6.
#pragma unroll
    for (int pp = 0; pp < 2; ++pp) {
      __syncthreads();
      if (wy == pp) {
        // C/D layout: col=lane&15, row=(lane>>4)*4+reg  [m89]
#pragma unroll
        for (int i = 0; i < 4; ++i)
#pragma unroll
          for (int j = 0; j < 4; ++j) {
            const int colw = (wx << 6) + (j << 4) + (lane & 15);
#pragma unroll
            for (int r = 0; r < 4; ++r) {
              const int row = (i << 4) + ((lane >> 4) << 2) + r;
              score[(row << 7) + ((((colw >> 2) ^ (row & 31)) << 2) | (colw & 3))] =
                  fmaf(-2.0f, acc[i][j][r], b2v[j]);
            }
          }
      }
      __syncthreads();
      {
        const int lr = tid & 63;             // query row within this pass
        const int qd = tid >> 6;             // quarter 0..3 (== wave id)
        const float* srow = score + (lr << 7);
        const int key = lr & 31;
        const int cb4 = qd << 3;
#pragma unroll 4
        for (int g = 0; g < 8; ++g) {
          const float4 v = *(const float4*)(srow + (((cb4 + g) ^ key) << 2));
          const int ib = m0 + (qd << 5) + (g << 2);
          if (pp == 0) {
            if (v.x < As9) CHAIN_P(A, v.x, ib);
            if (v.y < As9) CHAIN_P(A, v.y, ib + 1);
            if (v.z < As9) CHAIN_P(A, v.z, ib + 2);
            if (v.w < As9) CHAIN_P(A, v.w, ib + 3);
          } else {
            if (v.x < Bs9) CHAIN_P(B, v.x, ib);
            if (v.y < Bs9) CHAIN_P(B, v.y, ib + 1);
            if (v.z < Bs9) CHAIN_P(B, v.z, ib + 2);
            if (v.w < Bs9) CHAIN_P(B, v.w, ib + 3);
          }
        }
      }
    }
  }

  // merge the 4 quarter-scanners per query, two rounds (pass-A, pass-B queries)
  __syncthreads();
  float* mg = (float*)smem;
  {
    float* p_ = mg + tid * 20;
    p_[0] = As0; p_[1] = As1; p_[2] = As2; p_[3] = As3; p_[4] = As4;
    p_[5] = As5; p_[6] = As6; p_[7] = As7; p_[8] = As8; p_[9] = As9;
    int* q_ = (int*)(p_ + 10);
    q_[0] = Ai0; q_[1] = Ai1; q_[2] = Ai2; q_[3] = Ai3; q_[4] = Ai4;
    q_[5] = Ai5; q_[6] = Ai6; q_[7] = Ai7; q_[8] = Ai8; q_[9] = Ai9;
  }
  __syncthreads();
  if (tid < 64) {                            // owns quarter 0 of query tid
#pragma unroll
    for (int qd = 1; qd < 4; ++qd) {
      const float* p_ = mg + ((qd << 6) + tid) * 20;
      const int* q_ = (const int*)(p_ + 10);
#pragma unroll
      for (int q = 0; q < KNN; ++q) {
        const float v = p_[q];
        const int ix = q_[q];
        if (v < As9) CHAIN_P(A, v, ix);
      }
    }
    const size_t base = ((size_t)(n0 + tid) * NCHUNK + chunk) * KNN;
    cand_s[base + 0] = As0; cand_s[base + 1] = As1; cand_s[base + 2] = As2;
    cand_s[base + 3] = As3; cand_s[base + 4] = As4; cand_s[base + 5] = As5;
    cand_s[base + 6] = As6; cand_s[base + 7] = As7; cand_s[base + 8] = As8;
    cand_s[base + 9] = As9;
    cand_i[base + 0] = Ai0; cand_i[base + 1] = Ai1; cand_i[base + 2] = Ai2;
    cand_i[base + 3] = Ai3; cand_i[base + 4] = Ai4; cand_i[base + 5] = Ai5;
    cand_i[base + 6] = Ai6; cand_i[base + 7] = Ai7; cand_i[base + 8] = Ai8;
    cand_i[base + 9] = Ai9;
  }
  __syncthreads();
  {
    float* p_ = mg + tid * 20;
    p_[0] = Bs0; p_[1] = Bs1; p_[2] = Bs2; p_[3] = Bs3; p_[4] = Bs4;
    p_[5] = Bs5; p_[6] = Bs6; p_[7] = Bs7; p_[8] = Bs8; p_[9] = Bs9;
    int* q_ = (int*)(p_ + 10);
    q_[0] = Bi0; q_[1] = Bi1; q_[2] = Bi2; q_[3] = Bi3; q_[4] = Bi4;
    q_[5] = Bi5; q_[6] = Bi6; q_[7] = Bi7; q_[8] = Bi8; q_[9] = Bi9;
  }
  __syncthreads();
  if (tid < 64) {
#pragma unroll
    for (int qd = 1; qd < 4; ++qd) {
      const float* p_ = mg + ((qd << 6) + tid) * 20;
      const int* q_ = (const int*)(p_ + 10);
#pragma unroll
      for (int q = 0; q < KNN; ++q) {
        const float v = p_[q];
        const int ix = q_[q];
        if (v < Bs9) CHAIN_P(B, v, ix);
      }
    }
    const size_t base = ((size_t)(n0 + 64 + tid) * NCHUNK + chunk) * KNN;
    cand_s[base + 0] = Bs0; cand_s[base + 1] = Bs1; cand_s[base + 2] = Bs2;
    cand_s[base + 3] = Bs3; cand_s[base + 4] = Bs4; cand_s[base + 5] = Bs5;
    cand_s[base + 6] = Bs6; cand_s[base + 7] = Bs7; cand_s[base + 8] = Bs8;
    cand_s[base + 9] = Bs9;
    cand_i[base + 0] = Bi0; cand_i[base + 1] = Bi1; cand_i[base + 2] = Bi2;
    cand_i[base + 3] = Bi3; cand_i[base + 4] = Bi4; cand_i[base + 5] = Bi5;
    cand_i[base + 6] = Bi6; cand_i[base + 7] = Bi7; cand_i[base + 8] = Bi8;
    cand_i[base + 9] = Bi9;
  }
}

// ---------------- phase 1 (fallback, round-3 proven): in-kernel conversion ----
__global__ __launch_bounds__(256, 2) void knn_chunk_fallback(
    const float* __restrict__ Ag, const float* __restrict__ Bg,
    const float* __restrict__ b2g, float* __restrict__ cand_s,
    int* __restrict__ cand_i) {
  __shared__ float smemf[64 * 130];
  char* lds = (char*)smemf;
  float (*S64)[130] = (float(*)[130])smemf;

  const int tid = threadIdx.x;
  const int lane = tid & 63;
  const int wave = tid >> 6;
  const int wx = wave & 1, wy = wave >> 1;
  const int n0 = blockIdx.y * BN;
  const int chunk = blockIdx.x;

  float ts[KNN];
  int ti_[KNN];
#pragma unroll
  for (int q = 0; q < KNN; ++q) { ts[q] = 3.0e38f; ti_[q] = -1; }

  for (int sub = 0; sub < NSUB; ++sub) {
    const int m0 = (chunk * NSUB + sub) * BM;
    float4v acc[4][4];
#pragma unroll
    for (int i = 0; i < 4; ++i)
#pragma unroll
      for (int j = 0; j < 4; ++j) acc[i][j] = (float4v)(0.0f);

    for (int k0 = 0; k0 < D; k0 += 32) {
      __syncthreads();
#pragma unroll
      for (int r = 0; r < 4; ++r) {
        const int id = tid + (r << 8);
        const int n = id >> 3;
        const int c4 = id & 7;
        const int k = c4 << 2;
        const int off = ((n >> 4) << 10) + (((n & 15) | ((k >> 3) << 4)) << 4) +
                        ((c4 & 1) << 3);
        {
          const float4 v = *(const float4*)(Ag + (size_t)(n0 + n) * D + k0 + k);
          const half2v h01 = __builtin_amdgcn_cvt_pkrtz(v.x, v.y);
          const half2v h23 = __builtin_amdgcn_cvt_pkrtz(v.z, v.w);
          const half2v l01 =
              __builtin_amdgcn_cvt_pkrtz(v.x - (float)h01.x, v.y - (float)h01.y);
          const half2v l23 =
              __builtin_amdgcn_cvt_pkrtz(v.z - (float)h23.x, v.w - (float)h23.y);
          union { half2v h[2]; uint2 u; } hh, ll;
          hh.h[0] = h01; hh.h[1] = h23;
          ll.h[0] = l01; ll.h[1] = l23;
          *(uint2*)(lds + off) = hh.u;
          *(uint2*)(lds + 8192 + off) = ll.u;
        }
        {
          const float4 v = *(const float4*)(Bg + (size_t)(m0 + n) * D + k0 + k);
          const half2v h01 = __builtin_amdgcn_cvt_pkrtz(v.x, v.y);
          const half2v h23 = __builtin_amdgcn_cvt_pkrtz(v.z, v.w);
          const half2v l01 =
              __builtin_amdgcn_cvt_pkrtz(v.x - (float)h01.x, v.y - (float)h01.y);
          const half2v l23 =
              __builtin_amdgcn_cvt_pkrtz(v.z - (float)h23.x, v.w - (float)h23.y);
          union { half2v h[2]; uint2 u; } hh, ll;
          hh.h[0] = h01; hh.h[1] = h23;
          ll.h[0] = l01; ll.h[1] = l23;
          *(uint2*)(lds + 16384 + off) = hh.u;
          *(uint2*)(lds + 24576 + off) = ll.u;
        }
      }
      __syncthreads();
      half8 ah[4], al[4], bh[4], bl[4];
#pragma unroll
      for (int q = 0; q < 4; ++q) {
        const int ao = ((((wy << 2) + q) << 10)) + (lane << 4);
        ah[q] = *(half8*)(lds + ao);
        al[q] = *(half8*)(lds + 8192 + ao);
        const int bo = ((((wx << 2) + q) << 10)) + (lane << 4);
        bh[q] = *(half8*)(lds + 16384 + bo);
        bl[q] = *(half8*)(lds + 24576 + bo);
      }
#pragma unroll
      for (int i = 0; i < 4; ++i)
#pragma unroll
        for (int j = 0; j < 4; ++j) {
          acc[i][j] = __builtin_amdgcn_mfma_f32_16x16x32_f16(ah[i], bh[j], acc[i][j], 0, 0, 0);
          acc[i][j] = __builtin_amdgcn_mfma_f32_16x16x32_f16(ah[i], bl[j], acc[i][j], 0, 0, 0);
          acc[i][j] = __builtin_amdgcn_mfma_f32_16x16x32_f16(al[i], bh[j], acc[i][j], 0, 0, 0);
        }
    }

    float b2v[4];
#pragma unroll
    for (int j = 0; j < 4; ++j)
      b2v[j] = b2g[m0 + (wx << 6) + (j << 4) + (lane & 15)];

    for (int p = 0; p < 2; ++p) {
      __syncthreads();
      if (wy == p) {
#pragma unroll
        for (int i = 0; i < 4; ++i)
#pragma unroll
          for (int j = 0; j < 4; ++j)
#pragma unroll
            for (int r = 0; r < 4; ++r)
              S64[(i << 4) + ((lane >> 4) << 2) + r]
                 [(wx << 6) + (j << 4) + (lane & 15)] =
                  fmaf(-2.0f, acc[i][j][r], b2v[j]);
      }
      __syncthreads();
      const int rr = tid & 127;
      if ((rr >> 6) == p) {
        const int lr = rr & 63;
        const int cbase = (tid >> 7) << 6;
        float cut = ts[KNN - 1];
        for (int c = 0; c < 64; ++c) {
          const float s = S64[lr][cbase + c];
          if (s < cut) {
            float cs = s;
            int ci = m0 + cbase + c;
#pragma unroll
            for (int q = 0; q < KNN; ++q) {
              if (cs < ts[q]) {
                const float tf = ts[q]; ts[q] = cs; cs = tf;
                const int tv = ti_[q]; ti_[q] = ci; ci = tv;
              }
            }
            cut = ts[KNN - 1];
          }
        }
      }
    }
  }

  __syncthreads();
  const int r = tid & 127, h = tid >> 7;
  float* mg = (float*)smemf;
  if (h == 1) {
#pragma unroll
    for (int q = 0; q < KNN; ++q) {
      mg[r * 20 + q] = ts[q];
      ((int*)mg)[r * 20 + 10 + q] = ti_[q];
    }
  }
  __syncthreads();
  if (h == 0) {
#pragma unroll
    for (int q = 0; q < KNN; ++q) {
      const float s = mg[r * 20 + q];
      const int idx = ((int*)mg)[r * 20 + 10 + q];
      if (s < ts[KNN - 1]) {
        float cs = s;
        int ci = idx;
#pragma unroll
        for (int u = 0; u < KNN; ++u) {
          if (cs < ts[u]) {
            const float tf = ts[u]; ts[u] = cs; cs = tf;
            const int tv = ti_[u]; ti_[u] = ci; ci = tv;
          }
        }
      }
    }
    const size_t base = ((size_t)(n0 + r) * NCHUNK + chunk) * KNN;
#pragma unroll
    for (int q = 0; q < KNN; ++q) {
      cand_s[base + q] = ts[q];
      cand_i[base + q] = ti_[q];
    }
  }
}

// ---------------- phase 2: global top-10 merge + probs mean + argmax ----------------
__global__ __launch_bounds__(256) void knn_finalize_kernel(
    const float* __restrict__ cand_s, const int* __restrict__ cand_i,
    const float* __restrict__ probs, float* __restrict__ out) {
  const int n = blockIdx.x, t = threadIdx.x;
  const size_t cb = (size_t)n * CAND_PER_N;

  float sc[5];
  int id_[5];
#pragma unroll
  for (int r = 0; r < 5; ++r) {
    sc[r] = cand_s[cb + t + (r << 8)];
    id_[r] = cand_i[cb + t + (r << 8)];
  }

  __shared__ float rs[4];
  __shared__ int rm[4];
  __shared__ int win[KNN];

  for (int round = 0; round < KNN; ++round) {
    float bs = 3.0e38f;
    int bm = 0x7fffffff;
#pragma unroll
    for (int r = 0; r < 5; ++r) {
      const bool better =
          (id_[r] >= 0) && (sc[r] < bs || (sc[r] == bs && id_[r] < bm));
      if (better) { bs = sc[r]; bm = id_[r]; }
    }
#pragma unroll
    for (int off = 32; off >= 1; off >>= 1) {
      const float os = __shfl_down(bs, off);
      const int om = __shfl_down(bm, off);
      if (os < bs || (os == bs && om < bm)) { bs = os; bm = om; }
    }
    if ((t & 63) == 0) { rs[t >> 6] = bs; rm[t >> 6] = bm; }
    __syncthreads();
    if (t == 0) {
      float fb = rs[0]; int fm = rm[0];
      for (int w = 1; w < 4; ++w)
        if (rs[w] < fb || (rs[w] == fb && rm[w] < fm)) { fb = rs[w]; fm = rm[w]; }
      win[round] = fm;
    }
    __syncthreads();
    const int wmv = win[round];
#pragma unroll
    for (int r = 0; r < 5; ++r)
      if (id_[r] == wmv) id_[r] = -1;  // m indices are globally unique
  }

  __shared__ float pv[128];
  float myp = -1.0e30f;
  if (t < C) {
    float acc = 0.0f;
#pragma unroll
    for (int q = 0; q < KNN; ++q) acc += probs[(size_t)win[q] * C + t];
    myp = acc * (1.0f / KNN);
    out[N + (size_t)n * C + t] = myp;
  }
  if (t < 128) pv[t] = myp;
  __syncthreads();
  if (t == 0) {
    float bv = pv[0];
    int bi = 0;
    for (int c = 1; c < C; ++c)
      if (pv[c] > bv) { bv = pv[c]; bi = c; }
    out[n] = (float)bi;
  }
}

extern "C" void kernel_launch(void* const* d_in, const int* in_sizes, int n_in,
                              void* d_out, int out_size, void* d_ws, size_t ws_size,
                              hipStream_t stream) {
  const float* features = (const float*)d_in[0];  // (N, D)
  const float* bank = (const float*)d_in[1];      // (M, D)
  const float* probs = (const float*)d_in[2];     // (M, C)
  float* out = (float*)d_out;                     // [labels(N) | probs(N*C)]

  // ws layout (fast path):
  // b2 (0.5 MB) | cand_s (10.5 MB) | cand_i (10.5 MB) | Ahi,Alo (1 MB ea) | Bhi,Blo (64 MB ea)
  float* b2 = (float*)d_ws;
  float* cand_s = b2 + M;
  int* cand_i = (int*)(cand_s + (size_t)N * CAND_PER_N);
  char* Ahi = (char*)(cand_i + (size_t)N * CAND_PER_N);
  char* Alo = Ahi + (size_t)N * D * 2;
  char* Bhi = Alo + (size_t)N * D * 2;
  char* Blo = Bhi + (size_t)M * D * 2;
  const size_t NEED_FAST =
      (size_t)M * 4 + (size_t)N * CAND_PER_N * 8 + (size_t)N * D * 4 + (size_t)M * D * 4;

  if (ws_size >= NEED_FAST) {
    cvt_kernel<<<(N * 32) / 256, 256, 0, stream>>>(features, Ahi, Alo, nullptr);
    cvt_kernel<<<(M * 32) / 256, 256, 0, stream>>>(bank, Bhi, Blo, b2);  // fused b2
    knn_chunk_mfma<<<dim3(NCHUNK, N / BN), 256, 0, stream>>>(Ahi, Alo, Bhi, Blo,
                                                             b2, cand_s, cand_i);
  } else {
    b2_kernel<<<M / 4, 256, 0, stream>>>(bank, b2);
    knn_chunk_fallback<<<dim3(NCHUNK, N / BN), 256, 0, stream>>>(features, bank,
                                                                 b2, cand_s, cand_i);
  }
  knn_finalize_kernel<<<N, 256, 0, stream>>>(cand_s, cand_i, probs, out);
}